// Round 6
// baseline (2103.284 us; speedup 1.0000x reference)
//
#include <hip/hip_runtime.h>
#include <cstddef>

// (B, C, D, H, W) = (2, 2, 128, 256, 256)
#define BZ   2
#define DV   128
#define HV   256
#define WV   256
#define NP   32
#define NBOX 64                 // BZ*NP seed boxes
#define RAD  10
#define BOX  21                 // 2*RAD+1
#define BOX2 441
#define BOX3 9261
#define HWV  65536
#define DHW  ((size_t)DV*HWV)
#define SMOOTH 1e-5f
#define NT   448                // 7 waves; 441 active (one per (h,w))

// One evolution step: field S -> T via separable 3x3x3 box sum * p[d].
// Two distinct LDS arrays per pass (no in-place aliasing -> batched reads,
// single waitcnt). All addresses are (const + t): 2-way bank alias = free.
// Per-thread state: p[21] + scalars only (round-5 spill lesson).
#define ONE_ITER(S, T_, TRK9, TRKN)                                         \
    do {                                                                    \
        if (act) {                                                          \
            _Pragma("unroll")                                               \
            for (int d = 0; d < BOX; ++d) {                                 \
                float lv = (S)[d*BOX2 + tm1];                               \
                float cv = (S)[d*BOX2 + t];                                 \
                float rv = (S)[d*BOX2 + tp1];                               \
                (T_)[d*BOX2 + t] = (wl ? lv : 0.f) + cv + (wr ? rv : 0.f);  \
            }                                                               \
        }                                                                   \
        __syncthreads();                                                    \
        if (act) {                                                          \
            _Pragma("unroll")                                               \
            for (int d = 0; d < BOX; ++d) {                                 \
                float av = (T_)[d*BOX2 + hm1];                              \
                float cv = (T_)[d*BOX2 + t];                                \
                float bv = (T_)[d*BOX2 + hp1];                              \
                (S)[d*BOX2 + t] = (hl ? av : 0.f) + cv + (hr ? bv : 0.f);   \
            }                                                               \
        }                                                                   \
        __syncthreads();                                                    \
        if (act) {                                                          \
            _Pragma("unroll")                                               \
            for (int d = 0; d < BOX; ++d) {                                 \
                float s2 = (S)[d*BOX2 + t];                                 \
                if (d > 0)      s2 += (S)[(d-1)*BOX2 + t];                  \
                if (d < BOX-1)  s2 += (S)[(d+1)*BOX2 + t];                  \
                float v = s2 * p[d];                                        \
                (T_)[d*BOX2 + t] = v;                                       \
                if (TRK9) max9 = fmaxf(max9, v);                            \
                if (TRKN) maxN = fmaxf(maxN, v);                            \
            }                                                               \
        }                                                                   \
        __syncthreads();                                                    \
    } while (0)

// ===========================================================================
// Single kernel, 64 blocks (one per seed box). Evolve u_k in LDS (ping-pong
// X/Y), then atomic-counter arrival; last block computes overlap-corrected
// g_N (rare), the eps recurrence t_N = g_N + eps*g_9, and the eb gather.
__global__ void __launch_bounds__(NT)
cape_kernel(const float* __restrict__ logits,
            const int* __restrict__ ea,
            const int* __restrict__ eb,
            float* __restrict__ out,
            float* __restrict__ u,        // [NBOX][BOX3] d*441 + h*21 + w
            float* __restrict__ g9part,   // [NBOX]
            float* __restrict__ gNpart,   // [NBOX]
            unsigned int* __restrict__ counter)
{
    __shared__ float X[BOX3];             // 37044 B
    __shared__ float Y[BOX3];             // 37044 B
    __shared__ int sE[NBOX][3];
    __shared__ float sred[7], sred2[7];
    __shared__ int sflag, stail;

    const int box = blockIdx.x;
    const int b = box >> 5;
    const int t = threadIdx.x;
    const bool act = (t < BOX2);
    const int hh = t / BOX, ww = t % BOX;

    // Stage all seeds in LDS (coalesced), then ballot-based dup detection.
    if (t < NBOX*3) ((int*)sE)[t] = ea[t];
    __syncthreads();
    const int sd = sE[box][0], sh = sE[box][1], sw = sE[box][2];
    if (t < 64) {
        const int pidx = box - b*NP;
        bool pr = false;
        if (t < pidx) {
            int q = b*NP + t;
            pr = (sE[q][0]==sd && sE[q][1]==sh && sE[q][2]==sw);
        }
        unsigned long long m = __ballot(pr);
        if (t == 0) sflag = (m != 0ull);
    }
    __syncthreads();
    const bool dup = (sflag != 0);        // duplicate seed: contributes once

    float max9 = 0.f, maxN = 0.f;

    if (!dup) {
        // Clamped neighbor offsets (edge contributions zeroed by selects).
        const bool wl = (ww > 0), wr = (ww < BOX-1);
        const bool hl = (hh > 0), hr = (hh < BOX-1);
        const int tm1 = t + (wl ? -1 : 0);
        const int tp1 = t + (wr ?  1 : 0);
        const int hm1 = t + (hl ? -BOX : 0);
        const int hp1 = t + (hr ?  BOX : 0);

        // prob column, pre-scaled by 1/27; zero outside the volume.
        float p[BOX];
        #pragma unroll
        for (int d = 0; d < BOX; ++d) p[d] = 0.f;
        if (act) {
            const int gh = sh - RAD + hh, gw = sw - RAD + ww;
            if (gh >= 0 && gh < HV && gw >= 0 && gw < WV) {
                const float* lg = logits + (size_t)b * 2 * DHW;
                #pragma unroll
                for (int d = 0; d < BOX; ++d) {
                    int gd = sd - RAD + d;
                    if (gd >= 0 && gd < DV) {
                        size_t off = (size_t)gd * HWV + (size_t)gh * WV + gw;
                        float l0 = lg[off], l1 = lg[off + DHW];
                        p[d] = (1.f/27.f) / (1.f + __expf(l0 - l1));
                    }
                }
            }
        }

        // Analytic u_1: pool(delta)*prob = p[d] on the 3^3 cube at center.
        if (act) {
            #pragma unroll
            for (int d = 0; d < BOX; ++d) {
                bool in3 = (d >= RAD-1 && d <= RAD+1) &&
                           (hh >= RAD-1 && hh <= RAD+1) &&
                           (ww >= RAD-1 && ww <= RAD+1);
                X[d*BOX2 + t] = in3 ? p[d] : 0.f;
            }
        }
        __syncthreads();

        // Steps m=1..8 (u_2..u_9) as 4 double-steps; track u_9 max on the
        // last half. Then step m=9 (u_10) X->Y with u_10 max. Field ends in Y.
        for (int kk = 0; kk < 4; ++kk) {
            ONE_ITER(X, Y, false, false);
            ONE_ITER(Y, X, (kk == 3), false);
        }
        ONE_ITER(X, Y, false, true);

        // Write final field to global (coalesced) + reduce per-box maxes.
        for (int i = t; i < BOX3; i += NT) u[(size_t)box * BOX3 + i] = Y[i];

        #pragma unroll
        for (int o = 32; o > 0; o >>= 1) {
            max9 = fmaxf(max9, __shfl_down(max9, o));
            maxN = fmaxf(maxN, __shfl_down(maxN, o));
        }
        if ((t & 63) == 0) { sred[t >> 6] = max9; sred2[t >> 6] = maxN; }
        __syncthreads();
        if (t == 0) {
            float m9 = sred[0], mN = sred2[0];
            #pragma unroll
            for (int i = 1; i < 7; ++i) { m9 = fmaxf(m9, sred[i]); mN = fmaxf(mN, sred2[i]); }
            g9part[box] = m9;
            gNpart[box] = mN;     // exact unless another box's field overlaps
        }
    } else {
        if (t == 0) { g9part[box] = 0.f; gNpart[box] = 0.f; }
    }

    // ---- arrival: last block runs the tail --------------------------------
    if (t == 0) {
        __threadfence();
        unsigned int old = atomicAdd(counter, 1u);
        stail = (old == NBOX - 1) ? 1 : 0;
    }
    __syncthreads();
    if (!stail) return;
    __threadfence();   // acquire: all blocks' u/g writes visible

    // ---- tail: overlap-corrected g_N, recurrence, gather ------------------
    __shared__ int sdup[NBOX], sovl[NBOX];
    __shared__ float sg9[NBOX], sgN[NBOX];
    __shared__ float bgN[BZ], bg9[BZ];
    if (t < NBOX) {
        sg9[t] = g9part[t];
        sgN[t] = gNpart[t];
        int bb = t >> 5, dd = 0;
        for (int q = bb*NP; q < t; ++q)
            if (sE[q][0]==sE[t][0] && sE[q][1]==sE[t][1] && sE[q][2]==sE[t][2])
                { dd = 1; break; }
        sdup[t] = dd;
    }
    __syncthreads();
    if (t < NBOX) {
        int ov = 0;
        if (!sdup[t]) {
            int bb = t >> 5;
            for (int q = bb*NP; q < (bb+1)*NP; ++q) {
                if (q == t || sdup[q]) continue;
                if (abs(sE[q][0]-sE[t][0]) <= 2*RAD &&
                    abs(sE[q][1]-sE[t][1]) <= 2*RAD &&
                    abs(sE[q][2]-sE[t][2]) <= 2*RAD) { ov = 1; break; }
            }
        }
        sovl[t] = ov;
    }
    __syncthreads();
    // Recompute summed-field max for overlapped boxes (expected: rare).
    for (int q = 0; q < NBOX; ++q) {
        if (!sovl[q]) continue;                 // shared -> block-uniform
        int bb = q >> 5;
        float m = 0.f;
        for (int i = t; i < BOX3; i += NT) {
            int d = i / BOX2, r = i % BOX2;
            int h = r / BOX, w = r % BOX;
            float v = u[(size_t)q * BOX3 + i];
            int gd = sE[q][0] - RAD + d, gh = sE[q][1] - RAD + h, gw = sE[q][2] - RAD + w;
            for (int j = bb*NP; j < (bb+1)*NP; ++j) {
                if (j == q || sdup[j]) continue;
                int ld = gd - sE[j][0] + RAD;
                int lh = gh - sE[j][1] + RAD;
                int lw = gw - sE[j][2] + RAD;
                if (ld >= 0 && ld < BOX && lh >= 0 && lh < BOX && lw >= 0 && lw < BOX)
                    v += u[(size_t)j * BOX3 + (ld*BOX + lh)*BOX + lw];
            }
            m = fmaxf(m, v);
        }
        #pragma unroll
        for (int o = 32; o > 0; o >>= 1) m = fmaxf(m, __shfl_down(m, o));
        if ((t & 63) == 0) sred[t >> 6] = m;
        __syncthreads();
        if (t == 0) {
            float mm = sred[0];
            #pragma unroll
            for (int i = 1; i < 7; ++i) mm = fmaxf(mm, sred[i]);
            sgN[q] = mm;
        }
        __syncthreads();
    }
    if (t < BZ) {
        float gN = 0.f, g9 = 0.f;
        for (int q = t*NP; q < (t+1)*NP; ++q) {
            gN = fmaxf(gN, sgN[q]);
            g9 = fmaxf(g9, sg9[q]);
        }
        bgN[t] = gN; bg9[t] = g9;
    }
    __syncthreads();
    // eb gather + reduce (wave 0). t_N = g_N + eps*g_9 (eps^2 terms <1e-10).
    if (t < 64) {
        int bb = t >> 5;
        float tden = bgN[bb] + SMOOTH * bg9[bb];
        int d = eb[t*3], h = eb[t*3+1], w = eb[t*3+2];
        float v = 0.f;
        for (int q = bb*NP; q < (bb+1)*NP; ++q) {
            if (sdup[q]) continue;
            int ld = d - sE[q][0] + RAD;
            int lh = h - sE[q][1] + RAD;
            int lw = w - sE[q][2] + RAD;
            if (ld >= 0 && ld < BOX && lh >= 0 && lh < BOX && lw >= 0 && lw < BOX)
                v += u[(size_t)q * BOX3 + (ld*BOX + lh)*BOX + lw];
        }
        float score = (tden > 0.f) ? v / tden : 0.f;  // gN==0 => dead field
        #pragma unroll
        for (int o = 32; o > 0; o >>= 1) score += __shfl_down(score, o);
        if (t == 0) out[0] = 1.f - score / (float)NBOX;
    }
}

// ===========================================================================
extern "C" void kernel_launch(void* const* d_in, const int* in_sizes, int n_in,
                              void* d_out, int out_size, void* d_ws, size_t ws_size,
                              hipStream_t stream) {
    const float* logits = (const float*)d_in[0];
    // d_in[1] = labels (host-side only)
    const int* ea = (const int*)d_in[2];
    const int* eb = (const int*)d_in[3];
    float* out = (float*)d_out;

    float* u       = (float*)d_ws;                   // 64*9261 floats (~2.3 MB)
    float* g9part  = u + (size_t)NBOX * BOX3;        // 64
    float* gNpart  = g9part + NBOX;                  // 64
    unsigned int* counter = (unsigned int*)(gNpart + NBOX);

    hipMemsetAsync(counter, 0, sizeof(unsigned int), stream);
    cape_kernel<<<NBOX, NT, 0, stream>>>(logits, ea, eb, out,
                                         u, g9part, gNpart, counter);
}

// Round 7
// 244.298 us; speedup vs baseline: 8.6095x; 8.6095x over previous
//
#include <hip/hip_runtime.h>
#include <cstddef>

// (B, C, D, H, W) = (2, 2, 128, 256, 256)
#define BZ   2
#define DV   128
#define HV   256
#define WV   256
#define NP   32
#define NBOX 64                 // BZ*NP seed boxes
#define RAD  10
#define BOX  21                 // 2*RAD+1
#define BOX2 441
#define BOX3 9261
#define HWV  65536
#define DHW  ((size_t)DV*HWV)
#define SMOOTH 1e-5f
#define NT   448                // 7 waves; 441 active (one per (h,w))

// One evolution step: field S -> T via separable 3x3x3 box sum * p[d].
// Two distinct LDS arrays per pass (no in-place aliasing -> batched reads,
// single waitcnt). All addresses are (const + t): <=2-way bank alias = free.
#define ONE_ITER(S, T_, TRK9, TRKN)                                         \
    do {                                                                    \
        if (act) {                                                          \
            _Pragma("unroll")                                               \
            for (int d = 0; d < BOX; ++d) {                                 \
                float lv = (S)[d*BOX2 + tm1];                               \
                float cv = (S)[d*BOX2 + t];                                 \
                float rv = (S)[d*BOX2 + tp1];                               \
                (T_)[d*BOX2 + t] = (wl ? lv : 0.f) + cv + (wr ? rv : 0.f);  \
            }                                                               \
        }                                                                   \
        __syncthreads();                                                    \
        if (act) {                                                          \
            _Pragma("unroll")                                               \
            for (int d = 0; d < BOX; ++d) {                                 \
                float av = (T_)[d*BOX2 + hm1];                              \
                float cv = (T_)[d*BOX2 + t];                                \
                float bv = (T_)[d*BOX2 + hp1];                              \
                (S)[d*BOX2 + t] = (hl ? av : 0.f) + cv + (hr ? bv : 0.f);   \
            }                                                               \
        }                                                                   \
        __syncthreads();                                                    \
        if (act) {                                                          \
            _Pragma("unroll")                                               \
            for (int d = 0; d < BOX; ++d) {                                 \
                float s2 = (S)[d*BOX2 + t];                                 \
                if (d > 0)      s2 += (S)[(d-1)*BOX2 + t];                  \
                if (d < BOX-1)  s2 += (S)[(d+1)*BOX2 + t];                  \
                float v = s2 * p[d];                                        \
                (T_)[d*BOX2 + t] = v;                                       \
                if (TRK9) max9 = fmaxf(max9, v);                            \
                if (TRKN) maxN = fmaxf(maxN, v);                            \
            }                                                               \
        }                                                                   \
        __syncthreads();                                                    \
    } while (0)

// ===========================================================================
// K1: one block per seed box. Evolve u_k = avgpool3(u_{k-1})*prob for 9
// steps from analytic u_1, ping-pong LDS. Emits final field, per-box max of
// u_9 (eps term), own-box max of u_10, and dup flag.
__global__ void __launch_bounds__(NT)
evolve_kernel(const float* __restrict__ logits,
              const int* __restrict__ ea,
              float* __restrict__ u,        // [NBOX][BOX3] d*441 + h*21 + w
              float* __restrict__ g9part,   // [NBOX]
              float* __restrict__ gNpart,   // [NBOX]
              int* __restrict__ dupflag)    // [NBOX]
{
    __shared__ float X[BOX3];
    __shared__ float Y[BOX3];
    __shared__ int sE[NBOX][3];
    __shared__ float sred[7], sred2[7];
    __shared__ int sflag;

    const int box = blockIdx.x;
    const int b = box >> 5;
    const int t = threadIdx.x;
    const bool act = (t < BOX2);
    const int hh = t / BOX, ww = t % BOX;

    if (t < NBOX*3) ((int*)sE)[t] = ea[t];
    __syncthreads();
    const int sd = sE[box][0], sh = sE[box][1], sw = sE[box][2];
    if (t < 64) {
        const int pidx = box - b*NP;
        bool pr = false;
        if (t < pidx) {
            int q = b*NP + t;
            pr = (sE[q][0]==sd && sE[q][1]==sh && sE[q][2]==sw);
        }
        unsigned long long m = __ballot(pr);
        if (t == 0) sflag = (m != 0ull);
    }
    __syncthreads();

    if (sflag) {   // duplicate seed contributes once (.set semantics)
        if (t == 0) { g9part[box] = 0.f; gNpart[box] = 0.f; dupflag[box] = 1; }
        return;
    }
    if (t == 0) dupflag[box] = 0;

    const bool wl = (ww > 0), wr = (ww < BOX-1);
    const bool hl = (hh > 0), hr = (hh < BOX-1);
    const int tm1 = t + (wl ? -1 : 0);
    const int tp1 = t + (wr ?  1 : 0);
    const int hm1 = t + (hl ? -BOX : 0);
    const int hp1 = t + (hr ?  BOX : 0);

    // prob column pre-scaled by 1/27; zero outside the volume.
    float p[BOX];
    #pragma unroll
    for (int d = 0; d < BOX; ++d) p[d] = 0.f;
    if (act) {
        const int gh = sh - RAD + hh, gw = sw - RAD + ww;
        if (gh >= 0 && gh < HV && gw >= 0 && gw < WV) {
            const float* lg = logits + (size_t)b * 2 * DHW;
            #pragma unroll
            for (int d = 0; d < BOX; ++d) {
                int gd = sd - RAD + d;
                if (gd >= 0 && gd < DV) {
                    size_t off = (size_t)gd * HWV + (size_t)gh * WV + gw;
                    float l0 = lg[off], l1 = lg[off + DHW];
                    p[d] = (1.f/27.f) / (1.f + __expf(l0 - l1));
                }
            }
        }
    }

    // Analytic u_1: pool(delta)*prob = p[d] on the 3^3 cube at the center.
    if (act) {
        #pragma unroll
        for (int d = 0; d < BOX; ++d) {
            bool in3 = (d >= RAD-1 && d <= RAD+1) &&
                       (hh >= RAD-1 && hh <= RAD+1) &&
                       (ww >= RAD-1 && ww <= RAD+1);
            X[d*BOX2 + t] = in3 ? p[d] : 0.f;
        }
    }
    __syncthreads();

    float max9 = 0.f, maxN = 0.f;
    // u_2..u_9 as 4 double-steps (track u_9 max), then u_10 into Y.
    for (int kk = 0; kk < 4; ++kk) {
        ONE_ITER(X, Y, false, false);
        ONE_ITER(Y, X, (kk == 3), false);
    }
    ONE_ITER(X, Y, false, true);

    for (int i = t; i < BOX3; i += NT) u[(size_t)box * BOX3 + i] = Y[i];

    #pragma unroll
    for (int o = 32; o > 0; o >>= 1) {
        max9 = fmaxf(max9, __shfl_down(max9, o));
        maxN = fmaxf(maxN, __shfl_down(maxN, o));
    }
    if ((t & 63) == 0) { sred[t >> 6] = max9; sred2[t >> 6] = maxN; }
    __syncthreads();
    if (t == 0) {
        float m9 = sred[0], mN = sred2[0];
        #pragma unroll
        for (int i = 1; i < 7; ++i) { m9 = fmaxf(m9, sred[i]); mN = fmaxf(mN, sred2[i]); }
        g9part[box] = m9;
        gNpart[box] = mN;   // exact unless another box's field overlaps (K2)
    }
}

// ===========================================================================
// K2: per-box overlap correction, parallel across 64 blocks (the round-6
// lesson: never serialize this in one block). For boxes with overlap
// neighbors: own tile -> LDS, accumulate each neighbor's intersection region
// (uniform bounds, coalesced-ish, no per-voxel branching), max-reduce.
__global__ void __launch_bounds__(NT)
maxsum_kernel(const int* __restrict__ ea,
              const float* __restrict__ u,
              const int* __restrict__ dupflag,
              float* __restrict__ gNpart)
{
    __shared__ float L[BOX3];
    __shared__ int sE[NBOX][3];
    __shared__ int sdup[NBOX];
    __shared__ int list[NP], ldel[NP][3];
    __shared__ int nlist;
    __shared__ float sred[7];

    const int box = blockIdx.x;
    const int b = box >> 5;
    const int t = threadIdx.x;

    if (t < NBOX*3) ((int*)sE)[t] = ea[t];
    if (t >= NT-NBOX) sdup[t-(NT-NBOX)] = dupflag[t-(NT-NBOX)];
    __syncthreads();
    if (sdup[box]) return;                       // gNpart stays 0

    if (t == 0) {
        int n = 0;
        const int sd = sE[box][0], sh = sE[box][1], sw = sE[box][2];
        for (int q = b*NP; q < (b+1)*NP; ++q) {
            if (q == box || sdup[q]) continue;
            int dd = sd - sE[q][0], dh = sh - sE[q][1], dw = sw - sE[q][2];
            if (abs(dd) <= 2*RAD && abs(dh) <= 2*RAD && abs(dw) <= 2*RAD) {
                list[n] = q;
                ldel[n][0] = dd; ldel[n][1] = dh; ldel[n][2] = dw;
                ++n;
            }
        }
        nlist = n;
    }
    __syncthreads();
    const int nl = nlist;
    if (nl == 0) return;                         // evolve's own-box max exact

    for (int i = t; i < BOX3; i += NT) L[i] = u[(size_t)box * BOX3 + i];
    __syncthreads();

    for (int j = 0; j < nl; ++j) {
        const int dd = ldel[j][0], dh = ldel[j][1], dw = ldel[j][2];
        const int lod = max(0, -dd), hid = min(BOX, BOX - dd);
        const int loh = max(0, -dh), hih = min(BOX, BOX - dh);
        const int low = max(0, -dw), hiw = min(BOX, BOX - dw);
        const int ed = hid - lod, eh = hih - loh, ew = hiw - low;
        const int vol = ed * eh * ew;
        const float* uj = u + (size_t)list[j] * BOX3;
        for (int i = t; i < vol; i += NT) {
            int dl = lod + i / (eh * ew), r = i % (eh * ew);
            int hlq = loh + r / ew, wlq = low + r % ew;
            int own = dl*BOX2 + hlq*BOX + wlq;
            int jid = (dl+dd)*BOX2 + (hlq+dh)*BOX + (wlq+dw);
            L[own] += uj[jid];
        }
        __syncthreads();   // different j's intersections may share voxels
    }

    float m = 0.f;
    for (int i = t; i < BOX3; i += NT) m = fmaxf(m, L[i]);
    #pragma unroll
    for (int o = 32; o > 0; o >>= 1) m = fmaxf(m, __shfl_down(m, o));
    if ((t & 63) == 0) sred[t >> 6] = m;
    __syncthreads();
    if (t == 0) {
        float mm = sred[0];
        #pragma unroll
        for (int i = 1; i < 7; ++i) mm = fmaxf(mm, sred[i]);
        gNpart[box] = mm;
    }
}

// ===========================================================================
// K3: t_N = g_N + eps*g_9 (higher eps powers < 1e-10 relative);
// score = sum-over-covering-boxes u_10[eb] / t_N;  out = 1 - mean(score).
__global__ void final_kernel(const int* __restrict__ ea,
                             const int* __restrict__ eb,
                             const float* __restrict__ u,
                             const int* __restrict__ dupflag,
                             const float* __restrict__ gNpart,
                             const float* __restrict__ g9part,
                             float* __restrict__ out)
{
    const int t = threadIdx.x;   // 64 threads = 1 wave: (b, pair)
    const int b = t >> 5;
    float gN = 0.f, g9 = 0.f;
    for (int q = b*NP; q < (b+1)*NP; ++q) {
        gN = fmaxf(gN, gNpart[q]);
        g9 = fmaxf(g9, g9part[q]);
    }
    const float tden = gN + SMOOTH * g9;

    const int d = eb[t*3], h = eb[t*3+1], w = eb[t*3+2];
    float v = 0.f;
    for (int q = b*NP; q < (b+1)*NP; ++q) {
        if (dupflag[q]) continue;
        int ld = d - ea[q*3]   + RAD;
        int lh = h - ea[q*3+1] + RAD;
        int lw = w - ea[q*3+2] + RAD;
        if (ld >= 0 && ld < BOX && lh >= 0 && lh < BOX && lw >= 0 && lw < BOX)
            v += u[(size_t)q * BOX3 + (ld*BOX + lh)*BOX + lw];
    }
    float score = (tden > 0.f) ? v / tden : 0.f;  // gN==0 => field dead => 0
    #pragma unroll
    for (int o = 32; o > 0; o >>= 1) score += __shfl_down(score, o);
    if (t == 0) out[0] = 1.f - score / (float)NBOX;
}

// ===========================================================================
extern "C" void kernel_launch(void* const* d_in, const int* in_sizes, int n_in,
                              void* d_out, int out_size, void* d_ws, size_t ws_size,
                              hipStream_t stream) {
    const float* logits = (const float*)d_in[0];
    // d_in[1] = labels (host-side only)
    const int* ea = (const int*)d_in[2];
    const int* eb = (const int*)d_in[3];
    float* out = (float*)d_out;

    float* u       = (float*)d_ws;                   // 64*9261 floats (~2.3 MB)
    float* g9part  = u + (size_t)NBOX * BOX3;        // 64
    float* gNpart  = g9part + NBOX;                  // 64
    int*   dflag   = (int*)(gNpart + NBOX);          // 64

    evolve_kernel<<<NBOX, NT, 0, stream>>>(logits, ea, u, g9part, gNpart, dflag);
    maxsum_kernel<<<NBOX, NT, 0, stream>>>(ea, u, dflag, gNpart);
    final_kernel<<<1, 64, 0, stream>>>(ea, eb, u, dflag, gNpart, g9part, out);
}

// Round 8
// 239.263 us; speedup vs baseline: 8.7907x; 1.0210x over previous
//
#include <hip/hip_runtime.h>
#include <cstddef>

// (B, C, D, H, W) = (2, 2, 128, 256, 256)
#define BZ   2
#define DV   128
#define HV   256
#define WV   256
#define NP   32
#define NBOX 64                 // BZ*NP seed boxes
#define RAD  10
#define BOX  21                 // 2*RAD+1
#define BOX2 441
#define BOX3 9261
#define HWV  65536
#define DHW  ((size_t)DV*HWV)
#define SMOOTH 1e-5f
#define NT   448                // 7 waves; 441 active (one per (h,w))
#define CST  21                 // LDS column stride: odd -> conflict-free

// ===========================================================================
// K1: one block per seed box. Field lives as per-thread register d-columns
// (d-axis pool sum costs zero LDS). w/h neighbor exchange via two ping-pong
// LDS column buffers; 126 LDS ops + 2 barriers per iteration.
__global__ void __launch_bounds__(NT, 2)
evolve_kernel(const float* __restrict__ logits,
              const int* __restrict__ ea,
              float* __restrict__ u,        // [NBOX][BOX3] d*441 + h*21 + w
              float* __restrict__ g9part,   // [NBOX]
              float* __restrict__ gNpart,   // [NBOX]
              int* __restrict__ dupflag)    // [NBOX]
{
    __shared__ float A[BOX2 * CST];         // 37044 B
    __shared__ float Bb[BOX2 * CST];        // 37044 B
    __shared__ int sE[NBOX][3];
    __shared__ float sred[7], sred2[7];
    __shared__ int sflag;

    const int box = blockIdx.x;
    const int b = box >> 5;
    const int t = threadIdx.x;
    const bool act = (t < BOX2);
    const int hh = t / BOX, ww = t % BOX;

    if (t < NBOX*3) ((int*)sE)[t] = ea[t];
    __syncthreads();
    const int sd = sE[box][0], sh = sE[box][1], sw = sE[box][2];
    if (t < 64) {
        const int pidx = box - b*NP;
        bool pr = false;
        if (t < pidx) {
            int q = b*NP + t;
            pr = (sE[q][0]==sd && sE[q][1]==sh && sE[q][2]==sw);
        }
        unsigned long long m = __ballot(pr);
        if (t == 0) sflag = (m != 0ull);
    }
    __syncthreads();

    if (sflag) {   // duplicate seed contributes once (.set semantics)
        if (t == 0) { g9part[box] = 0.f; gNpart[box] = 0.f; dupflag[box] = 1; }
        return;
    }
    if (t == 0) dupflag[box] = 0;

    const bool wl = (ww > 0), wr = (ww < BOX-1);
    const bool hl = (hh > 0), hr = (hh < BOX-1);

    // prob column pre-scaled by 1/27; zero outside the volume.
    float p[BOX];
    #pragma unroll
    for (int d = 0; d < BOX; ++d) p[d] = 0.f;
    if (act) {
        const int gh = sh - RAD + hh, gw = sw - RAD + ww;
        if (gh >= 0 && gh < HV && gw >= 0 && gw < WV) {
            const float* lg = logits + (size_t)b * 2 * DHW;
            #pragma unroll
            for (int d = 0; d < BOX; ++d) {
                int gd = sd - RAD + d;
                if (gd >= 0 && gd < DV) {
                    size_t off = (size_t)gd * HWV + (size_t)gh * WV + gw;
                    float l0 = lg[off], l1 = lg[off + DHW];
                    p[d] = (1.f/27.f) / (1.f + __expf(l0 - l1));
                }
            }
        }
    }

    // Analytic u_1 = pool(delta)*prob: p[d] on the 3^3 cube at the center.
    float c[BOX];
    {
        const bool inhw = (hh >= RAD-1 && hh <= RAD+1) && (ww >= RAD-1 && ww <= RAD+1);
        #pragma unroll
        for (int d = 0; d < BOX; ++d)
            c[d] = (inhw && d >= RAD-1 && d <= RAD+1) ? p[d] : 0.f;
    }

    float max9 = 0.f, maxN = 0.f;
    float* const myA = &A[t * CST];
    float* const myB = &Bb[t * CST];

    // 9 steps: c = u_1 -> u_10. Iter k produces u_{k+2}.
    for (int k = 0; k < 9; ++k) {
        // d-sums in registers (ring, in place)
        float prev = 0.f, cur = c[0];
        #pragma unroll
        for (int d = 0; d < BOX; ++d) {
            float nxt = (d < BOX-1) ? c[d+1] : 0.f;
            c[d] = prev + cur + nxt;
            prev = cur; cur = nxt;
        }
        // write own column to A
        if (act) {
            #pragma unroll
            for (int d = 0; d < BOX; ++d) myA[d] = c[d];
        }
        __syncthreads();
        // w-pass: add w+-1 neighbor columns from A, write to B
        if (act) {
            if (wl) {
                const float* nb = myA - CST;
                #pragma unroll
                for (int d = 0; d < BOX; ++d) c[d] += nb[d];
            }
            if (wr) {
                const float* nb = myA + CST;
                #pragma unroll
                for (int d = 0; d < BOX; ++d) c[d] += nb[d];
            }
            #pragma unroll
            for (int d = 0; d < BOX; ++d) myB[d] = c[d];
        }
        __syncthreads();
        // h-pass: add h+-1 neighbor columns from B, multiply prob
        if (act) {
            if (hl) {
                const float* nb = myB - BOX*CST;
                #pragma unroll
                for (int d = 0; d < BOX; ++d) c[d] += nb[d];
            }
            if (hr) {
                const float* nb = myB + BOX*CST;
                #pragma unroll
                for (int d = 0; d < BOX; ++d) c[d] += nb[d];
            }
        }
        #pragma unroll
        for (int d = 0; d < BOX; ++d) {
            c[d] *= p[d];
            if (k == 7) max9 = fmaxf(max9, c[d]);   // u_9
            if (k == 8) maxN = fmaxf(maxN, c[d]);   // u_10
        }
        // next iter's A-writes are fenced from this iter's A-reads by the
        // second sync; B-reads above are fenced from next B-writes by the
        // next iteration's first sync.
    }

    // write final field from registers (coalesced: fixed d, consecutive t)
    if (act) {
        #pragma unroll
        for (int d = 0; d < BOX; ++d)
            u[(size_t)box * BOX3 + d * BOX2 + t] = c[d];
    }

    #pragma unroll
    for (int o = 32; o > 0; o >>= 1) {
        max9 = fmaxf(max9, __shfl_down(max9, o));
        maxN = fmaxf(maxN, __shfl_down(maxN, o));
    }
    if ((t & 63) == 0) { sred[t >> 6] = max9; sred2[t >> 6] = maxN; }
    __syncthreads();
    if (t == 0) {
        float m9 = sred[0], mN = sred2[0];
        #pragma unroll
        for (int i = 1; i < 7; ++i) { m9 = fmaxf(m9, sred[i]); mN = fmaxf(mN, sred2[i]); }
        g9part[box] = m9;
        gNpart[box] = mN;   // exact unless another box's field overlaps (K2)
    }
}

// ===========================================================================
// K2: per-box overlap correction, parallel across 64 blocks. Own tile ->
// LDS, accumulate each neighbor's intersection region (uniform bounds),
// max-reduce. Early-exit when no overlap neighbors (common case).
__global__ void __launch_bounds__(NT)
maxsum_kernel(const int* __restrict__ ea,
              const float* __restrict__ u,
              const int* __restrict__ dupflag,
              float* __restrict__ gNpart)
{
    __shared__ float L[BOX3];
    __shared__ int sE[NBOX][3];
    __shared__ int sdup[NBOX];
    __shared__ int list[NP], ldel[NP][3];
    __shared__ int nlist;
    __shared__ float sred[7];

    const int box = blockIdx.x;
    const int b = box >> 5;
    const int t = threadIdx.x;

    if (t < NBOX*3) ((int*)sE)[t] = ea[t];
    if (t >= NT-NBOX) sdup[t-(NT-NBOX)] = dupflag[t-(NT-NBOX)];
    __syncthreads();
    if (sdup[box]) return;                       // gNpart stays 0

    if (t == 0) {
        int n = 0;
        const int sd = sE[box][0], sh = sE[box][1], sw = sE[box][2];
        for (int q = b*NP; q < (b+1)*NP; ++q) {
            if (q == box || sdup[q]) continue;
            int dd = sd - sE[q][0], dh = sh - sE[q][1], dw = sw - sE[q][2];
            if (abs(dd) <= 2*RAD && abs(dh) <= 2*RAD && abs(dw) <= 2*RAD) {
                list[n] = q;
                ldel[n][0] = dd; ldel[n][1] = dh; ldel[n][2] = dw;
                ++n;
            }
        }
        nlist = n;
    }
    __syncthreads();
    const int nl = nlist;
    if (nl == 0) return;                         // evolve's own-box max exact

    for (int i = t; i < BOX3; i += NT) L[i] = u[(size_t)box * BOX3 + i];
    __syncthreads();

    for (int j = 0; j < nl; ++j) {
        const int dd = ldel[j][0], dh = ldel[j][1], dw = ldel[j][2];
        const int lod = max(0, -dd), hid = min(BOX, BOX - dd);
        const int loh = max(0, -dh), hih = min(BOX, BOX - dh);
        const int low = max(0, -dw), hiw = min(BOX, BOX - dw);
        const int ed = hid - lod, eh = hih - loh, ew = hiw - low;
        const int vol = ed * eh * ew;
        const float* uj = u + (size_t)list[j] * BOX3;
        for (int i = t; i < vol; i += NT) {
            int dl = lod + i / (eh * ew), r = i % (eh * ew);
            int hlq = loh + r / ew, wlq = low + r % ew;
            int own = dl*BOX2 + hlq*BOX + wlq;
            int jid = (dl+dd)*BOX2 + (hlq+dh)*BOX + (wlq+dw);
            L[own] += uj[jid];
        }
        __syncthreads();   // different j's intersections may share voxels
    }

    float m = 0.f;
    for (int i = t; i < BOX3; i += NT) m = fmaxf(m, L[i]);
    #pragma unroll
    for (int o = 32; o > 0; o >>= 1) m = fmaxf(m, __shfl_down(m, o));
    if ((t & 63) == 0) sred[t >> 6] = m;
    __syncthreads();
    if (t == 0) {
        float mm = sred[0];
        #pragma unroll
        for (int i = 1; i < 7; ++i) mm = fmaxf(mm, sred[i]);
        gNpart[box] = mm;
    }
}

// ===========================================================================
// K3: t_N = g_N + eps*g_9 (higher eps powers < 1e-10 relative);
// score = sum-over-covering-boxes u_10[eb] / t_N;  out = 1 - mean(score).
__global__ void final_kernel(const int* __restrict__ ea,
                             const int* __restrict__ eb,
                             const float* __restrict__ u,
                             const int* __restrict__ dupflag,
                             const float* __restrict__ gNpart,
                             const float* __restrict__ g9part,
                             float* __restrict__ out)
{
    const int t = threadIdx.x;   // 64 threads = 1 wave: (b, pair)
    const int b = t >> 5;
    float gN = 0.f, g9 = 0.f;
    for (int q = b*NP; q < (b+1)*NP; ++q) {
        gN = fmaxf(gN, gNpart[q]);
        g9 = fmaxf(g9, g9part[q]);
    }
    const float tden = gN + SMOOTH * g9;

    const int d = eb[t*3], h = eb[t*3+1], w = eb[t*3+2];
    float v = 0.f;
    for (int q = b*NP; q < (b+1)*NP; ++q) {
        if (dupflag[q]) continue;
        int ld = d - ea[q*3]   + RAD;
        int lh = h - ea[q*3+1] + RAD;
        int lw = w - ea[q*3+2] + RAD;
        if (ld >= 0 && ld < BOX && lh >= 0 && lh < BOX && lw >= 0 && lw < BOX)
            v += u[(size_t)q * BOX3 + (ld*BOX + lh)*BOX + lw];
    }
    float score = (tden > 0.f) ? v / tden : 0.f;  // gN==0 => field dead => 0
    #pragma unroll
    for (int o = 32; o > 0; o >>= 1) score += __shfl_down(score, o);
    if (t == 0) out[0] = 1.f - score / (float)NBOX;
}

// ===========================================================================
extern "C" void kernel_launch(void* const* d_in, const int* in_sizes, int n_in,
                              void* d_out, int out_size, void* d_ws, size_t ws_size,
                              hipStream_t stream) {
    const float* logits = (const float*)d_in[0];
    // d_in[1] = labels (host-side only)
    const int* ea = (const int*)d_in[2];
    const int* eb = (const int*)d_in[3];
    float* out = (float*)d_out;

    float* u       = (float*)d_ws;                   // 64*9261 floats (~2.3 MB)
    float* g9part  = u + (size_t)NBOX * BOX3;        // 64
    float* gNpart  = g9part + NBOX;                  // 64
    int*   dflag   = (int*)(gNpart + NBOX);          // 64

    evolve_kernel<<<NBOX, NT, 0, stream>>>(logits, ea, u, g9part, gNpart, dflag);
    maxsum_kernel<<<NBOX, NT, 0, stream>>>(ea, u, dflag, gNpart);
    final_kernel<<<1, 64, 0, stream>>>(ea, eb, u, dflag, gNpart, g9part, out);
}

// Round 9
// 238.795 us; speedup vs baseline: 8.8079x; 1.0020x over previous
//
#include <hip/hip_runtime.h>
#include <cstddef>

// (B, C, D, H, W) = (2, 2, 128, 256, 256)
#define BZ   2
#define DV   128
#define HV   256
#define WV   256
#define NP   32
#define NBOX 64                 // BZ*NP seed boxes
#define RAD  10
#define BOX  21                 // 2*RAD+1
#define BOX2 441
#define BOX3 9261
#define HWV  65536
#define DHW  ((size_t)DV*HWV)
#define SMOOTH 1e-5f
#define NT   448                // 7 waves; 441 active (one per (h,w))
#define CST  21                 // LDS column stride: odd -> conflict-free

// ===========================================================================
// K1: one block per seed box. Field lives as per-thread register d-columns
// (d-axis pool sum costs zero LDS). w/h neighbor exchange via two ping-pong
// LDS column buffers; 126 LDS ops + 2 barriers per iteration.  (Round-8
// verified: VGPR ~52-ish, no scratch, conflict-free.)
__global__ void __launch_bounds__(NT, 2)
evolve_kernel(const float* __restrict__ logits,
              const int* __restrict__ ea,
              float* __restrict__ u,        // [NBOX][BOX3] d*441 + h*21 + w
              float* __restrict__ g9part,   // [NBOX]
              float* __restrict__ gNpart,   // [NBOX]
              int* __restrict__ dupflag)    // [NBOX]
{
    __shared__ float A[BOX2 * CST];         // 37044 B
    __shared__ float Bb[BOX2 * CST];        // 37044 B
    __shared__ int sE[NBOX][3];
    __shared__ float sred[7], sred2[7];
    __shared__ int sflag;

    const int box = blockIdx.x;
    const int b = box >> 5;
    const int t = threadIdx.x;
    const bool act = (t < BOX2);
    const int hh = t / BOX, ww = t % BOX;

    if (t < NBOX*3) ((int*)sE)[t] = ea[t];
    __syncthreads();
    const int sd = sE[box][0], sh = sE[box][1], sw = sE[box][2];
    if (t < 64) {
        const int pidx = box - b*NP;
        bool pr = false;
        if (t < pidx) {
            int q = b*NP + t;
            pr = (sE[q][0]==sd && sE[q][1]==sh && sE[q][2]==sw);
        }
        unsigned long long m = __ballot(pr);
        if (t == 0) sflag = (m != 0ull);
    }
    __syncthreads();

    if (sflag) {   // duplicate seed contributes once (.set semantics)
        if (t == 0) { g9part[box] = 0.f; gNpart[box] = 0.f; dupflag[box] = 1; }
        return;
    }
    if (t == 0) dupflag[box] = 0;

    const bool wl = (ww > 0), wr = (ww < BOX-1);
    const bool hl = (hh > 0), hr = (hh < BOX-1);

    // prob column pre-scaled by 1/27; zero outside the volume.
    float p[BOX];
    #pragma unroll
    for (int d = 0; d < BOX; ++d) p[d] = 0.f;
    if (act) {
        const int gh = sh - RAD + hh, gw = sw - RAD + ww;
        if (gh >= 0 && gh < HV && gw >= 0 && gw < WV) {
            const float* lg = logits + (size_t)b * 2 * DHW;
            #pragma unroll
            for (int d = 0; d < BOX; ++d) {
                int gd = sd - RAD + d;
                if (gd >= 0 && gd < DV) {
                    size_t off = (size_t)gd * HWV + (size_t)gh * WV + gw;
                    float l0 = lg[off], l1 = lg[off + DHW];
                    p[d] = (1.f/27.f) / (1.f + __expf(l0 - l1));
                }
            }
        }
    }

    // Analytic u_1 = pool(delta)*prob: p[d] on the 3^3 cube at the center.
    float c[BOX];
    {
        const bool inhw = (hh >= RAD-1 && hh <= RAD+1) && (ww >= RAD-1 && ww <= RAD+1);
        #pragma unroll
        for (int d = 0; d < BOX; ++d)
            c[d] = (inhw && d >= RAD-1 && d <= RAD+1) ? p[d] : 0.f;
    }

    float max9 = 0.f, maxN = 0.f;
    float* const myA = &A[t * CST];
    float* const myB = &Bb[t * CST];

    // 9 steps: c = u_1 -> u_10. Iter k produces u_{k+2}.
    for (int k = 0; k < 9; ++k) {
        // d-sums in registers (ring, in place)
        float prev = 0.f, cur = c[0];
        #pragma unroll
        for (int d = 0; d < BOX; ++d) {
            float nxt = (d < BOX-1) ? c[d+1] : 0.f;
            c[d] = prev + cur + nxt;
            prev = cur; cur = nxt;
        }
        if (act) {
            #pragma unroll
            for (int d = 0; d < BOX; ++d) myA[d] = c[d];
        }
        __syncthreads();
        // w-pass: add w+-1 neighbor columns from A, write to B
        if (act) {
            if (wl) {
                const float* nb = myA - CST;
                #pragma unroll
                for (int d = 0; d < BOX; ++d) c[d] += nb[d];
            }
            if (wr) {
                const float* nb = myA + CST;
                #pragma unroll
                for (int d = 0; d < BOX; ++d) c[d] += nb[d];
            }
            #pragma unroll
            for (int d = 0; d < BOX; ++d) myB[d] = c[d];
        }
        __syncthreads();
        // h-pass: add h+-1 neighbor columns from B, multiply prob
        if (act) {
            if (hl) {
                const float* nb = myB - BOX*CST;
                #pragma unroll
                for (int d = 0; d < BOX; ++d) c[d] += nb[d];
            }
            if (hr) {
                const float* nb = myB + BOX*CST;
                #pragma unroll
                for (int d = 0; d < BOX; ++d) c[d] += nb[d];
            }
        }
        #pragma unroll
        for (int d = 0; d < BOX; ++d) {
            c[d] *= p[d];
            if (k == 7) max9 = fmaxf(max9, c[d]);   // u_9
            if (k == 8) maxN = fmaxf(maxN, c[d]);   // u_10
        }
    }

    // write final field from registers (coalesced: fixed d, consecutive t)
    if (act) {
        #pragma unroll
        for (int d = 0; d < BOX; ++d)
            u[(size_t)box * BOX3 + d * BOX2 + t] = c[d];
    }

    #pragma unroll
    for (int o = 32; o > 0; o >>= 1) {
        max9 = fmaxf(max9, __shfl_down(max9, o));
        maxN = fmaxf(maxN, __shfl_down(maxN, o));
    }
    if ((t & 63) == 0) { sred[t >> 6] = max9; sred2[t >> 6] = maxN; }
    __syncthreads();
    if (t == 0) {
        float m9 = sred[0], mN = sred2[0];
        #pragma unroll
        for (int i = 1; i < 7; ++i) { m9 = fmaxf(m9, sred[i]); mN = fmaxf(mN, sred2[i]); }
        g9part[box] = m9;
        gNpart[box] = mN;   // exact unless another box's field overlaps (K2)
    }
}

// ===========================================================================
// K2+K3 fused: per-box overlap correction parallel across 64 blocks
// (round-7 verified), then atomic-counter arrival; the LAST block runs the
// tiny gather tail (64 threads, ~2 us — unlike round 6's serialized
// correction, this tail is trivially small).
__global__ void __launch_bounds__(NT)
maxfin_kernel(const int* __restrict__ ea,
              const int* __restrict__ eb,
              const float* __restrict__ u,
              const int* __restrict__ dupflag,
              float* __restrict__ gNpart,
              const float* __restrict__ g9part,
              float* __restrict__ out,
              unsigned int* __restrict__ counter)
{
    __shared__ float L[BOX3];
    __shared__ int sE[NBOX][3];
    __shared__ int sdup[NBOX];
    __shared__ int list[NP], ldel[NP][3];
    __shared__ int nlist;
    __shared__ float sred[7];
    __shared__ int stail;

    const int box = blockIdx.x;
    const int b = box >> 5;
    const int t = threadIdx.x;

    if (t < NBOX*3) ((int*)sE)[t] = ea[t];
    if (t >= NT-NBOX) sdup[t-(NT-NBOX)] = dupflag[t-(NT-NBOX)];
    __syncthreads();

    // ---- overlap correction (skipped for dup / isolated boxes) ------------
    if (!sdup[box]) {
        if (t == 0) {
            int n = 0;
            const int sd = sE[box][0], sh = sE[box][1], sw = sE[box][2];
            for (int q = b*NP; q < (b+1)*NP; ++q) {
                if (q == box || sdup[q]) continue;
                int dd = sd - sE[q][0], dh = sh - sE[q][1], dw = sw - sE[q][2];
                if (abs(dd) <= 2*RAD && abs(dh) <= 2*RAD && abs(dw) <= 2*RAD) {
                    list[n] = q;
                    ldel[n][0] = dd; ldel[n][1] = dh; ldel[n][2] = dw;
                    ++n;
                }
            }
            nlist = n;
        }
        __syncthreads();
        const int nl = nlist;
        if (nl > 0) {
            for (int i = t; i < BOX3; i += NT) L[i] = u[(size_t)box * BOX3 + i];
            __syncthreads();
            for (int j = 0; j < nl; ++j) {
                const int dd = ldel[j][0], dh = ldel[j][1], dw = ldel[j][2];
                const int lod = max(0, -dd), hid = min(BOX, BOX - dd);
                const int loh = max(0, -dh), hih = min(BOX, BOX - dh);
                const int low = max(0, -dw), hiw = min(BOX, BOX - dw);
                const int ed = hid - lod, eh = hih - loh, ew = hiw - low;
                const int vol = ed * eh * ew;
                const float* uj = u + (size_t)list[j] * BOX3;
                for (int i = t; i < vol; i += NT) {
                    int dl = lod + i / (eh * ew), r = i % (eh * ew);
                    int hlq = loh + r / ew, wlq = low + r % ew;
                    L[dl*BOX2 + hlq*BOX + wlq] +=
                        uj[(dl+dd)*BOX2 + (hlq+dh)*BOX + (wlq+dw)];
                }
                __syncthreads();   // intersections of different j may overlap
            }
            float m = 0.f;
            for (int i = t; i < BOX3; i += NT) m = fmaxf(m, L[i]);
            #pragma unroll
            for (int o = 32; o > 0; o >>= 1) m = fmaxf(m, __shfl_down(m, o));
            if ((t & 63) == 0) sred[t >> 6] = m;
            __syncthreads();
            if (t == 0) {
                float mm = sred[0];
                #pragma unroll
                for (int i = 1; i < 7; ++i) mm = fmaxf(mm, sred[i]);
                gNpart[box] = mm;
            }
        }
    }

    // ---- arrival: last block runs the tiny gather tail --------------------
    if (t == 0) {
        __threadfence();
        unsigned int old = atomicAdd(counter, 1u);
        stail = (old == NBOX - 1) ? 1 : 0;
    }
    __syncthreads();
    if (!stail) return;
    __threadfence();   // acquire: all blocks' gNpart writes visible

    if (t < 64) {
        const int bb = t >> 5;
        float gN = 0.f, g9 = 0.f;
        for (int q = bb*NP; q < (bb+1)*NP; ++q) {
            gN = fmaxf(gN, gNpart[q]);
            g9 = fmaxf(g9, g9part[q]);
        }
        // t_N = g_N + eps*g_9 (higher eps powers < 1e-10 relative)
        const float tden = gN + SMOOTH * g9;
        const int d = eb[t*3], h = eb[t*3+1], w = eb[t*3+2];
        float v = 0.f;
        for (int q = bb*NP; q < (bb+1)*NP; ++q) {
            if (sdup[q]) continue;
            int ld = d - sE[q][0] + RAD;
            int lh = h - sE[q][1] + RAD;
            int lw = w - sE[q][2] + RAD;
            if (ld >= 0 && ld < BOX && lh >= 0 && lh < BOX && lw >= 0 && lw < BOX)
                v += u[(size_t)q * BOX3 + (ld*BOX + lh)*BOX + lw];
        }
        float score = (tden > 0.f) ? v / tden : 0.f;  // gN==0 => field dead
        #pragma unroll
        for (int o = 32; o > 0; o >>= 1) score += __shfl_down(score, o);
        if (t == 0) out[0] = 1.f - score / (float)NBOX;
    }
}

// ===========================================================================
extern "C" void kernel_launch(void* const* d_in, const int* in_sizes, int n_in,
                              void* d_out, int out_size, void* d_ws, size_t ws_size,
                              hipStream_t stream) {
    const float* logits = (const float*)d_in[0];
    // d_in[1] = labels (host-side only)
    const int* ea = (const int*)d_in[2];
    const int* eb = (const int*)d_in[3];
    float* out = (float*)d_out;

    float* u       = (float*)d_ws;                   // 64*9261 floats (~2.3 MB)
    float* g9part  = u + (size_t)NBOX * BOX3;        // 64
    float* gNpart  = g9part + NBOX;                  // 64
    int*   dflag   = (int*)(gNpart + NBOX);          // 64
    unsigned int* counter = (unsigned int*)(dflag + NBOX);

    hipMemsetAsync(counter, 0, sizeof(unsigned int), stream);
    evolve_kernel<<<NBOX, NT, 0, stream>>>(logits, ea, u, g9part, gNpart, dflag);
    maxfin_kernel<<<NBOX, NT, 0, stream>>>(ea, eb, u, dflag, gNpart, g9part,
                                           out, counter);
}